// Round 3
// baseline (324.084 us; speedup 1.0000x reference)
//
#include <hip/hip_runtime.h>

#define KDIM 8192
#define NDIM 16384
#define BDIM 16
#define NBLK 8                        // KDIM/1024 scale blocks per row
#define TN 8                          // output rows per wave
#define WAVES 4
#define ROWS_PER_BLOCK (TN * WAVES)   // 32

// out[16,16384] f32 = x[16,8192] f32 · dequant(qweight[16384,8192] int32(int8),
//                     scales[16384,8] f32 per-1024-block)^T + bias f32.
// One wave owns TN=8 consecutive output rows over full K. Lanes stride K in
// int4/float4 chunks (coalesced 1 KiB/instr/wave); acc[16][8] f32 in VGPRs;
// 64-lane butterfly reduce; lane 0 stores.
__global__ __launch_bounds__(256, 2) void int8lin_kernel(
    const float* __restrict__ x,
    const int* __restrict__ qw,
    const float* __restrict__ scales,
    const float* __restrict__ bias,
    float* __restrict__ out)
{
    const int lane = threadIdx.x & 63;
    const int wave = threadIdx.x >> 6;
    const int n0 = blockIdx.x * ROWS_PER_BLOCK + wave * TN;

    float acc[BDIM][TN];
#pragma unroll
    for (int i = 0; i < BDIM; ++i)
#pragma unroll
        for (int j = 0; j < TN; ++j) acc[i][j] = 0.f;

    const int kbase = lane * 4;       // 4 k-elements per lane per chunk

    for (int kb = 0; kb < KDIM; kb += 1024) {      // one scale block
        float s[TN];
#pragma unroll
        for (int j = 0; j < TN; ++j)
            s[j] = scales[(size_t)(n0 + j) * NBLK + (kb >> 10)];

#pragma unroll 1
        for (int kk = 0; kk < 1024; kk += 256) {   // 64 lanes * 4 k
            const int k0 = kb + kk + kbase;

            int4 w[TN];
#pragma unroll
            for (int j = 0; j < TN; ++j)
                w[j] = *reinterpret_cast<const int4*>(qw + (size_t)(n0 + j) * KDIM + k0);

            float wf[TN][4];
#pragma unroll
            for (int j = 0; j < TN; ++j) {
                wf[j][0] = (float)w[j].x * s[j];
                wf[j][1] = (float)w[j].y * s[j];
                wf[j][2] = (float)w[j].z * s[j];
                wf[j][3] = (float)w[j].w * s[j];
            }

#pragma unroll
            for (int i = 0; i < BDIM; ++i) {
                const float4 xv = *reinterpret_cast<const float4*>(x + (size_t)i * KDIM + k0);
#pragma unroll
                for (int j = 0; j < TN; ++j) {
                    acc[i][j] = fmaf(xv.x, wf[j][0], acc[i][j]);
                    acc[i][j] = fmaf(xv.y, wf[j][1], acc[i][j]);
                    acc[i][j] = fmaf(xv.z, wf[j][2], acc[i][j]);
                    acc[i][j] = fmaf(xv.w, wf[j][3], acc[i][j]);
                }
            }
        }
    }

    // 64-lane butterfly reduction per accumulator.
#pragma unroll
    for (int i = 0; i < BDIM; ++i)
#pragma unroll
        for (int j = 0; j < TN; ++j) {
            float v = acc[i][j];
#pragma unroll
            for (int off = 32; off >= 1; off >>= 1) v += __shfl_xor(v, off, 64);
            acc[i][j] = v;
        }

    if (lane == 0) {
#pragma unroll
        for (int j = 0; j < TN; ++j) {
            const float b = bias[n0 + j];
#pragma unroll
            for (int i = 0; i < BDIM; ++i)
                out[(size_t)i * NDIM + (n0 + j)] = acc[i][j] + b;
        }
    }
}

extern "C" void kernel_launch(void* const* d_in, const int* in_sizes, int n_in,
                              void* d_out, int out_size, void* d_ws, size_t ws_size,
                              hipStream_t stream) {
    const float* x      = (const float*)d_in[0];
    const int*   qw     = (const int*)d_in[1];
    const float* scales = (const float*)d_in[2];
    const float* bias   = (const float*)d_in[3];
    float*       out    = (float*)d_out;

    dim3 grid(NDIM / ROWS_PER_BLOCK);   // 512 blocks = 2 per CU
    dim3 block(256);                     // 4 waves
    int8lin_kernel<<<grid, block, 0, stream>>>(x, qw, scales, bias, out);
}